// Round 3
// baseline (217.193 us; speedup 1.0000x reference)
//
#include <hip/hip_runtime.h>

// EndEffectorLoss: rot6d -> R, FK over fixed 24-joint tree, end-effector MSE.
// R3: 5-task chain decomposition per pose; each wave = one straight-line chain
// (single live FK state, no spills, deep load pipelining). 640-thread blocks
// (10 waves = {A,B} x 5 chains, 64 frames) -> 30 waves/CU.
// pose [F,24,6] f32, offsets [F,24,3] f32, t_pose [24,3] f32. Out: 1 f32.
//
// Chains (joints 0/3/6/9 recomputed by 3 waves -- VALU is idle, L2 absorbs):
//   T0: 0-1-4-7    -> ee10   T1: 0-2-5-8    -> ee11
//   T2: 0-3-6-9-12 -> ee15
//   T3: 0-3-6-9-13-16-18-20 -> ee22
//   T4: 0-3-6-9-14-17-19-21 -> ee23

struct V3 { float x, y, z; };
struct M3 { float m[3][3]; };   // row r = basis vector b_r (row-stacked)

__device__ __forceinline__ V3 matvec(const M3& A, const V3& v) {
    return { A.m[0][0]*v.x + A.m[0][1]*v.y + A.m[0][2]*v.z,
             A.m[1][0]*v.x + A.m[1][1]*v.y + A.m[1][2]*v.z,
             A.m[2][0]*v.x + A.m[2][1]*v.y + A.m[2][2]*v.z };
}

__device__ __forceinline__ M3 matmul(const M3& A, const M3& B) {
    M3 C;
#pragma unroll
    for (int i = 0; i < 3; i++)
#pragma unroll
        for (int j = 0; j < 3; j++)
            C.m[i][j] = A.m[i][0]*B.m[0][j] + A.m[i][1]*B.m[1][j] + A.m[i][2]*B.m[2][j];
    return C;
}

// Pose joint J: 6 floats at frame + 6J; frame base 16B-aligned (576B/frame).
template<int J>
__device__ __forceinline__ M3 rot6d_j(const float* __restrict__ frame) {
    const float* p = frame + 6 * J;
    float v0, v1, v2, v3, v4, v5;
    if constexpr ((J & 1) == 0) {
        float4 a = *(const float4*)p;
        float2 b = *(const float2*)(p + 4);
        v0 = a.x; v1 = a.y; v2 = a.z; v3 = a.w; v4 = b.x; v5 = b.y;
    } else {
        float2 a = *(const float2*)p;
        float4 b = *(const float4*)(p + 2);
        v0 = a.x; v1 = a.y; v2 = b.x; v3 = b.y; v4 = b.z; v5 = b.w;
    }
    float n1 = v0*v0 + v1*v1 + v2*v2;
    float r1 = 1.0f / sqrtf(n1);
    V3 b1 = { v0*r1, v1*r1, v2*r1 };
    float d = b1.x*v3 + b1.y*v4 + b1.z*v5;
    V3 u = { v3 - d*b1.x, v4 - d*b1.y, v5 - d*b1.z };
    float n2 = u.x*u.x + u.y*u.y + u.z*u.z;
    float r2 = 1.0f / sqrtf(n2);
    V3 b2 = { u.x*r2, u.y*r2, u.z*r2 };
    V3 b3 = { b1.y*b2.z - b1.z*b2.y, b1.z*b2.x - b1.x*b2.z, b1.x*b2.y - b1.y*b2.x };
    M3 R;
    R.m[0][0]=b1.x; R.m[0][1]=b1.y; R.m[0][2]=b1.z;
    R.m[1][0]=b2.x; R.m[1][1]=b2.y; R.m[1][2]=b2.z;
    R.m[2][0]=b3.x; R.m[2][1]=b3.y; R.m[2][2]=b3.z;
    return R;
}

// Offset joint J: 3 floats at obase + 3J; obase 16B-aligned (288B/frame).
template<int J>
__device__ __forceinline__ V3 load_off_j(const float* __restrict__ obase) {
    const float* p = obase + 3 * J;
    if constexpr ((J & 1) == 0) {
        float2 a = *(const float2*)p;
        float  b = p[2];
        return { a.x, a.y, b };
    } else {
        float  a = p[0];
        float2 b = *(const float2*)(p + 1);
        return { a, b.x, b.y };
    }
}

struct FK { M3 o; V3 p; };

template<int J>
__device__ __forceinline__ FK fk_step(const float* __restrict__ frame,
                                      const float* __restrict__ obase,
                                      const FK& par) {
    V3 off = load_off_j<J>(obase);
    V3 t = matvec(par.o, off);
    FK s;
    s.p = { par.p.x + t.x, par.p.y + t.y, par.p.z + t.z };
    s.o = matmul(par.o, rot6d_j<J>(frame));
    return s;
}

template<int J>
__device__ __forceinline__ V3 fk_end(const float* __restrict__ obase, const FK& par) {
    V3 off = load_off_j<J>(obase);
    V3 t = matvec(par.o, off);
    return { par.p.x + t.x, par.p.y + t.y, par.p.z + t.z };
}

__global__ __launch_bounds__(640, 7)   // cap ~72 VGPR -> 30 waves/CU with 10-wave blocks
void ee_loss_kernel(const float* __restrict__ poseA, const float* __restrict__ poseB,
                    const float* __restrict__ offA,  const float* __restrict__ offB,
                    const float* __restrict__ tA,    const float* __restrict__ tB,
                    float* __restrict__ out, float inv_count) {
    const int tid  = threadIdx.x;
    const int wid  = tid >> 6;           // 0..9
    const int lane = tid & 63;
    const int task = wid >> 1;           // 0..4
    const bool isB = wid & 1;
    const long long f = (long long)blockIdx.x * 64 + lane;

    const float* frame = (isB ? poseB : poseA) + f * 144;
    const float* obase = (isB ? offB  : offA ) + f * 72;

    __shared__ float s_eeB[64][15];      // stride 15: gcd(15,32)=1, conflict-free
    __shared__ float s_inv[6];           // 1/scaleA(xyz), 1/scaleB(xyz)
    __shared__ float s_d[15];            // tB[ee]/sB - tA[ee]/sA
    __shared__ float s_part[5];

    // t_pose-derived constants (tiny, L2-resident); producers are in wave 0.
    if (tid < 6) {
        const float* tp = (tid < 3) ? tA : tB;
        int ax = (tid < 3) ? tid : tid - 3;
        float mn = tp[ax], mx = mn;
#pragma unroll
        for (int j = 1; j < 24; j++) {
            float v = tp[j*3 + ax];
            mn = fminf(mn, v); mx = fmaxf(mx, v);
        }
        s_inv[tid] = 1.0f / (mx - mn);
    }
    if (tid < 15) {
        const int EE[5] = {10, 11, 15, 22, 23};
        int e = tid / 3, ax = tid - 3*e;
        int j = EE[e];
        float mnA = tA[ax], mxA = mnA, mnB = tB[ax], mxB = mnB;
#pragma unroll
        for (int k = 1; k < 24; k++) {
            float a = tA[k*3 + ax], b = tB[k*3 + ax];
            mnA = fminf(mnA, a); mxA = fmaxf(mxA, a);
            mnB = fminf(mnB, b); mxB = fmaxf(mxB, b);
        }
        s_d[tid] = tB[j*3 + ax]/(mxB - mnB) - tA[j*3 + ax]/(mxA - mnA);
    }

    // One straight-line chain per wave (branches are wave-uniform).
    V3 e;
    {
        FK s; s.o = rot6d_j<0>(frame); s.p = load_off_j<0>(obase);
        if (task == 0) {
            s = fk_step<1>(frame, obase, s);
            s = fk_step<4>(frame, obase, s);
            s = fk_step<7>(frame, obase, s);
            e = fk_end<10>(obase, s);
        } else if (task == 1) {
            s = fk_step<2>(frame, obase, s);
            s = fk_step<5>(frame, obase, s);
            s = fk_step<8>(frame, obase, s);
            e = fk_end<11>(obase, s);
        } else if (task == 2) {
            s = fk_step<3>(frame, obase, s);
            s = fk_step<6>(frame, obase, s);
            s = fk_step<9>(frame, obase, s);
            s = fk_step<12>(frame, obase, s);
            e = fk_end<15>(obase, s);
        } else if (task == 3) {
            s = fk_step<3>(frame, obase, s);
            s = fk_step<6>(frame, obase, s);
            s = fk_step<9>(frame, obase, s);
            s = fk_step<13>(frame, obase, s);
            s = fk_step<16>(frame, obase, s);
            s = fk_step<18>(frame, obase, s);
            s = fk_step<20>(frame, obase, s);
            e = fk_end<22>(obase, s);
        } else {
            s = fk_step<3>(frame, obase, s);
            s = fk_step<6>(frame, obase, s);
            s = fk_step<9>(frame, obase, s);
            s = fk_step<14>(frame, obase, s);
            s = fk_step<17>(frame, obase, s);
            s = fk_step<19>(frame, obase, s);
            s = fk_step<21>(frame, obase, s);
            e = fk_end<23>(obase, s);
        }
    }

    const int col0 = task * 3;
    if (isB) {
        s_eeB[lane][col0 + 0] = e.x;
        s_eeB[lane][col0 + 1] = e.y;
        s_eeB[lane][col0 + 2] = e.z;
    }
    __syncthreads();

    float local = 0.0f;
    if (!isB) {
        float tx = e.x*s_inv[0] - s_eeB[lane][col0 + 0]*s_inv[3] + s_d[col0 + 0];
        float ty = e.y*s_inv[1] - s_eeB[lane][col0 + 1]*s_inv[4] + s_d[col0 + 1];
        float tz = e.z*s_inv[2] - s_eeB[lane][col0 + 2]*s_inv[5] + s_d[col0 + 2];
        local = (tx*tx + ty*ty + tz*tz) * inv_count;
#pragma unroll
        for (int off = 32; off > 0; off >>= 1)
            local += __shfl_down(local, off, 64);
        if (lane == 0) s_part[task] = local;
    }
    __syncthreads();
    if (tid == 0)
        atomicAdd(out, ((s_part[0] + s_part[1]) + (s_part[2] + s_part[3])) + s_part[4]);
}

extern "C" void kernel_launch(void* const* d_in, const int* in_sizes, int n_in,
                              void* d_out, int out_size, void* d_ws, size_t ws_size,
                              hipStream_t stream) {
    const float* poseA = (const float*)d_in[0];
    const float* poseB = (const float*)d_in[1];
    const float* offA  = (const float*)d_in[2];
    const float* offB  = (const float*)d_in[3];
    const float* tA    = (const float*)d_in[4];
    const float* tB    = (const float*)d_in[5];
    float* out = (float*)d_out;

    const int F = in_sizes[0] / 144;          // 65536
    const int blocks = F / 64;                // 64 frames/block, 10 waves/block
    const float inv_count = 1.0f / ((float)F * 15.0f);

    hipMemsetAsync(out, 0, sizeof(float), stream);
    ee_loss_kernel<<<blocks, 640, 0, stream>>>(poseA, poseB, offA, offB, tA, tB,
                                               out, inv_count);
}